// Round 3
// baseline (264.271 us; speedup 1.0000x reference)
//
#include <hip/hip_runtime.h>

// VQ-VAE forward: out = code_out[argmax_c(logits_c(x))], hard_idx = argmax.
// logits are piecewise-linear in scalar x (128 relu breakpoints). Per interval
// we build the UPPER ENVELOPE of the 512 affine logit lines (fp64-exact,
// branchless pairwise L/U-bound formulation), giving a piecewise-constant map
// x -> (idx, out). Samples do a 7-step LDS classify + short binary search.

#define B_SAMPLES 262144
#define HIDDEN    128
#define NUM_CODES 512
#define EMBED_DIM 256
#define NUM_INT   129   // HIDDEN + 1 intervals

// ---- workspace layout (byte offsets) ----
// 0       : t_sorted[128] double             (1 KB)
// 2048    : code_out[512] double             (4 KB)
// 8192    : env_cnt[129] int
// 9216    : surv[129*512] uchar              (64.5 KB)
// 75264   : Lx[129*512] double               (516 KB)
// 603648  : AB[129*512] double2              (1.03 MB)
// 1660416 : env_xs[129*512] double           (516 KB)
// 2188800 : env_idx[129*512] int             (258 KB)  -> total ~2.34 MB

__device__ __forceinline__ int classify(const double* ts, double xv) {
  int lo = 0, hi = HIDDEN;   // first index with ts[idx] > xv
  while (lo < hi) { int mid = (lo + hi) >> 1; if (ts[mid] > xv) hi = mid; else lo = mid + 1; }
  return lo;
}

__device__ __forceinline__ double wave_sum_f64(double s) {
  #pragma unroll
  for (int off = 32; off; off >>= 1) s += __shfl_xor(s, off);
  return s;
}

// P0a: sorted thresholds, code_out (wave-parallel coalesced), zero env_cnt.
__global__ void __launch_bounds__(256) k_prep(
    const float* __restrict__ w1, const float* __restrict__ b1,
    const float* __restrict__ emb, const float* __restrict__ decw,
    const float* __restrict__ decb, double* __restrict__ t_sorted,
    double* __restrict__ code_out, int* __restrict__ env_cnt) {
  __shared__ double tloc[HIDDEN];
  __shared__ double sdw[EMBED_DIM];
  const int tid = threadIdx.x;
  sdw[tid] = (double)decw[tid];                 // blockDim == EMBED_DIM == 256
  if (tid < HIDDEN) {
    double w = (double)w1[tid], b = (double)b1[tid];
    double t = -b / w;
    if (!isfinite(t)) t = 1e30;
    t = fmin(fmax(t, -1e30), 1e30);
    tloc[tid] = t;
  }
  if (tid < NUM_INT) env_cnt[tid] = 0;
  __syncthreads();
  if (tid < HIDDEN) {                           // stable rank sort, O(128^2)
    double t = tloc[tid];
    int r = 0;
    for (int k = 0; k < HIDDEN; ++k) {
      double tk = tloc[k];
      r += (tk < t) || (tk == t && k < tid);
    }
    t_sorted[r] = t;
  }
  const int w = tid >> 6, lane = tid & 63;
  const double dw0 = sdw[lane], dw1 = sdw[lane + 64],
               dw2 = sdw[lane + 128], dw3 = sdw[lane + 192];
  const double db = (double)decb[0];
  for (int c = w * 128; c < w * 128 + 128; ++c) {   // 4 waves x 128 codes
    const float* e = emb + c * EMBED_DIM;
    double s = (double)e[lane] * dw0;
    s = fma((double)e[lane + 64],  dw1, s);
    s = fma((double)e[lane + 128], dw2, s);
    s = fma((double)e[lane + 192], dw3, s);
    s = wave_sum_f64(s);
    if (lane == 0) code_out[c] = s + db;
  }
}

// P0b: per-interval affine (A,B) per code, wave-parallel coalesced.
__global__ void __launch_bounds__(256) k_tables(
    const float* __restrict__ w1, const float* __restrict__ b1,
    const float* __restrict__ w2, const float* __restrict__ b2,
    const double* __restrict__ t_sorted, double2* __restrict__ AB) {
  __shared__ double wj[HIDDEN], bj[HIDDEN];
  const int i = blockIdx.x;
  const int tid = threadIdx.x;
  double xm;
  if (i == 0)            xm = t_sorted[0] - 1.0;
  else if (i == HIDDEN)  xm = t_sorted[HIDDEN - 1] + 1.0;
  else                   xm = 0.5 * (t_sorted[i - 1] + t_sorted[i]);
  if (tid < HIDDEN) {
    double w = (double)w1[tid], b = (double)b1[tid];
    bool act = fma(w, xm, b) > 0.0;     // relu sign constant in open interval
    wj[tid] = act ? w : 0.0;
    bj[tid] = act ? b : 0.0;
  }
  __syncthreads();
  const int w = tid >> 6, lane = tid & 63;
  const double wa = wj[lane], wb2_ = wj[lane + 64];
  const double ba = bj[lane], bb2_ = bj[lane + 64];
  for (int c = w * 128; c < w * 128 + 128; ++c) {
    const float* r = w2 + c * HIDDEN;
    const double v0 = (double)r[lane], v1 = (double)r[lane + 64];
    double A  = fma(v1, wb2_, v0 * wa);
    double Bv = fma(v1, bb2_, v0 * ba);
    A  = wave_sum_f64(A);
    Bv = wave_sum_f64(Bv);
    if (lane == 0) AB[(i << 9) + c] = make_double2(A, Bv + (double)b2[c]);
  }
}

// P1: branchless pairwise envelope membership. Line l survives iff not
// dominated by an equal-slope line and L = max_{A_k<A_l} x* < U = min_{A_k>A_l} x*.
// L kept as fraction (nL,dL) with dL>=0 (dL==0 => -inf); U as (nU,dU) with
// dU<=0 (dU==0 => +inf; negative-denominator convention makes both compares
// use the same products n*den vs num*d).
// Block = 4 waves; wave w scans k in [w*128,(w+1)*128) (wave-uniform LDS
// broadcast reads); 8 blocks per interval each own 64 lines; LDS merge.
__global__ void __launch_bounds__(256) k_env1(const double2* __restrict__ AB,
                       unsigned char* __restrict__ surv, double* __restrict__ Lx,
                       int* __restrict__ env_cnt) {
  __shared__ double2 sAB[NUM_CODES];
  __shared__ double sNL[4][64], sDL[4][64], sNU[4][64], sDU[4][64];
  __shared__ int sDead[4][64];
  const int tid = threadIdx.x;
  const int i = blockIdx.x >> 3;        // interval
  const int g = blockIdx.x & 7;         // line group
  const int w = tid >> 6, lane = tid & 63;
  const int c = (g << 6) + lane;        // my line
  const double2* row = AB + (i << 9);
  for (int t = tid; t < NUM_CODES; t += 256) sAB[t] = row[t];
  __syncthreads();
  const double2 my = sAB[c];
  double nL = -1.0, dL = 0.0, nU = -1.0, dU = 0.0;
  int dead = 0;
  const int k0 = w << 7;
  #pragma unroll 4
  for (int kk = 0; kk < 128; ++kk) {
    const int k = k0 + kk;
    const double2 o = sAB[k];           // wave-uniform -> LDS broadcast
    const double d = my.x - o.x;        // A_l - A_k
    const double n = o.y - my.y;        // B_k - B_l   (x* = n/d)
    const bool condL = (d > 0.0) && (n * dL > nL * d);
    const bool condU = (d < 0.0) && (n * dU < nU * d);
    nL = condL ? n : nL;  dL = condL ? d : dL;
    nU = condU ? n : nU;  dU = condU ? d : dU;
    dead |= (d == 0.0) && ((n > 0.0) || (n == 0.0 && k < c));
  }
  sNL[w][lane] = nL; sDL[w][lane] = dL;
  sNU[w][lane] = nU; sDU[w][lane] = dU;
  sDead[w][lane] = dead;
  __syncthreads();
  if (tid < 64) {                       // wave 0 merges the 4 k-chunks
    #pragma unroll
    for (int wv = 1; wv < 4; ++wv) {
      double cn = sNL[wv][lane], cd = sDL[wv][lane];
      if (cn * dL > nL * cd) { nL = cn; dL = cd; }   // valid incl. 0-sentinels
      cn = sNU[wv][lane]; cd = sDU[wv][lane];
      if (cn * dU < nU * cd) { nU = cn; dU = cd; }
      dead |= sDead[wv][lane];
    }
    // L < U with dL>=0, dU<=0: multiply by dL*dU (<0) flips: nL*dU > nU*dL
    const int sv = (!dead) && (dL == 0.0 || dU == 0.0 || (nL * dU > nU * dL));
    const int pair = (i << 9) + c;
    surv[pair] = (unsigned char)sv;
    Lx[pair]   = (dL == 0.0) ? -1e300 : nL / dL;
    const unsigned long long m = __ballot(sv);
    if (lane == 0) atomicAdd(&env_cnt[i], (int)__popcll(m));
  }
}

// P2: compact survivors into per-interval slope-sorted segment tables.
// rank = #survivors with smaller slope (survivor slopes are distinct).
// Non-survivor slopes staged as +inf so the inner loop is one broadcast read.
__global__ void __launch_bounds__(256) k_env2(const double2* __restrict__ AB,
                       const unsigned char* __restrict__ surv,
                       const double* __restrict__ Lx,
                       double* __restrict__ env_xs, int* __restrict__ env_idx) {
  __shared__ double sA[NUM_CODES];
  const int tid = threadIdx.x;
  const int i = blockIdx.x >> 1;
  const int c = ((blockIdx.x & 1) << 8) + tid;
  const int base = i << 9;
  for (int t = tid; t < NUM_CODES; t += 256)
    sA[t] = surv[base + t] ? AB[base + t].x : 1e300;
  __syncthreads();
  const double myA = sA[c];
  int rank = 0;
  #pragma unroll 8
  for (int k = 0; k < NUM_CODES; ++k) rank += (sA[k] < myA) ? 1 : 0;
  if (surv[base + c]) {
    env_xs[base + rank]  = Lx[base + c];
    env_idx[base + rank] = c;
  }
}

// P3: per-sample lookup: classify interval (LDS), binary search segment starts.
__global__ void __launch_bounds__(256) k_map(const float* __restrict__ x,
                       const double* __restrict__ t_sorted,
                       const int* __restrict__ env_cnt,
                       const double* __restrict__ env_xs,
                       const int* __restrict__ env_idx,
                       const double* __restrict__ code_out,
                       float* __restrict__ out, float* __restrict__ idx_out) {
  __shared__ double ts[HIDDEN];
  __shared__ double sco[NUM_CODES];
  __shared__ int scnt[NUM_INT];
  const int tid = threadIdx.x;
  if (tid < HIDDEN) ts[tid] = t_sorted[tid];
  if (tid < NUM_INT) scnt[tid] = env_cnt[tid];
  for (int t = tid; t < NUM_CODES; t += 256) sco[t] = code_out[t];
  __syncthreads();
  const int s = blockIdx.x * 256 + tid;
  const double xv = (double)x[s];
  const int i = classify(ts, xv);
  const int base = i << 9;
  int lo = 0, hi = scnt[i] - 1;
  while (lo < hi) {                     // largest j with xs[j] <= xv
    const int mid = (lo + hi + 1) >> 1;
    if (env_xs[base + mid] <= xv) lo = mid; else hi = mid - 1;
  }
  const int ci = env_idx[base + lo];
  out[s]     = (float)sco[ci];
  idx_out[s] = (float)ci;
}

extern "C" void kernel_launch(void* const* d_in, const int* in_sizes, int n_in,
                              void* d_out, int out_size, void* d_ws, size_t ws_size,
                              hipStream_t stream) {
  const float* x    = (const float*)d_in[0];
  const float* w1   = (const float*)d_in[1];
  const float* b1   = (const float*)d_in[2];
  const float* w2   = (const float*)d_in[3];
  const float* b2   = (const float*)d_in[4];
  const float* emb  = (const float*)d_in[5];
  const float* decw = (const float*)d_in[6];
  const float* decb = (const float*)d_in[7];

  char* ws = (char*)d_ws;
  double*        t_sorted = (double*)        (ws + 0);
  double*        code_out = (double*)        (ws + 2048);
  int*           env_cnt  = (int*)           (ws + 8192);
  unsigned char* surv     = (unsigned char*) (ws + 9216);
  double*        Lx       = (double*)        (ws + 75264);
  double2*       AB       = (double2*)       (ws + 603648);
  double*        env_xs   = (double*)        (ws + 1660416);
  int*           env_idx  = (int*)           (ws + 2188800);

  float* out  = (float*)d_out;
  float* idxo = out + B_SAMPLES;

  k_prep  <<<1,               256, 0, stream>>>(w1, b1, emb, decw, decb, t_sorted, code_out, env_cnt);
  k_tables<<<NUM_INT,         256, 0, stream>>>(w1, b1, w2, b2, t_sorted, AB);
  k_env1  <<<NUM_INT * 8,     256, 0, stream>>>(AB, surv, Lx, env_cnt);
  k_env2  <<<NUM_INT * 2,     256, 0, stream>>>(AB, surv, Lx, env_xs, env_idx);
  k_map   <<<B_SAMPLES / 256, 256, 0, stream>>>(x, t_sorted, env_cnt, env_xs, env_idx, code_out, out, idxo);
}

// Round 4
// 137.830 us; speedup vs baseline: 1.9174x; 1.9174x over previous
//
#include <hip/hip_runtime.h>

// VQ-VAE forward: out = code_out[argmax_c(logits_c(x))], hard_idx = argmax.
// logits are piecewise-linear in scalar x (128 relu breakpoints). Per interval
// we build the UPPER ENVELOPE of the 512 affine logit lines (fp64-exact,
// branchless pairwise L/U-bound formulation), giving a piecewise-constant map
// x -> (idx, out). Samples do a 7-step LDS classify + short binary search.
// R3 lesson: NO cross-lane reductions in prep kernels -- per-thread fma
// chains with vectorized row streams instead (shuffle chains were 95% idle).

#define B_SAMPLES 262144
#define HIDDEN    128
#define NUM_CODES 512
#define EMBED_DIM 256
#define NUM_INT   129   // HIDDEN + 1 intervals

// ---- workspace layout (byte offsets) ----
// 0       : t_sorted[128] double             (1 KB)
// 2048    : code_out[512] double             (4 KB)
// 8192    : env_cnt[129] int
// 9216    : surv[129*512] uchar              (64.5 KB)
// 75264   : Lx[129*512] double               (516 KB)
// 603648  : AB[129*512] double2              (1.03 MB)
// 1660416 : env_xs[129*512] double           (516 KB)
// 2188800 : env_idx[129*512] int             (258 KB)  -> total ~2.34 MB

__device__ __forceinline__ int classify(const double* ts, double xv) {
  int lo = 0, hi = HIDDEN;   // first index with ts[idx] > xv
  while (lo < hi) { int mid = (lo + hi) >> 1; if (ts[mid] > xv) hi = mid; else lo = mid + 1; }
  return lo;
}

// P0a: sorted thresholds + zero env_cnt. One small block.
__global__ void __launch_bounds__(256) k_prep(
    const float* __restrict__ w1, const float* __restrict__ b1,
    double* __restrict__ t_sorted, int* __restrict__ env_cnt) {
  __shared__ double tloc[HIDDEN];
  const int tid = threadIdx.x;
  if (tid < HIDDEN) {
    double w = (double)w1[tid], b = (double)b1[tid];
    double t = -b / w;
    if (!isfinite(t)) t = 1e30;
    t = fmin(fmax(t, -1e30), 1e30);
    tloc[tid] = t;
  }
  if (tid < NUM_INT) env_cnt[tid] = 0;
  __syncthreads();
  if (tid < HIDDEN) {                     // stable rank sort, O(128^2)
    double t = tloc[tid];
    int r = 0;
    for (int k = 0; k < HIDDEN; ++k) {
      double tk = tloc[k];
      r += (tk < t) || (tk == t && k < tid);
    }
    t_sorted[r] = t;
  }
}

// P0b: code_out[c] = dot(emb[c], decw) + decb. Thread = code, float4 stream.
__global__ void __launch_bounds__(256) k_codeout(
    const float* __restrict__ emb, const float* __restrict__ decw,
    const float* __restrict__ decb, double* __restrict__ code_out) {
  __shared__ double sdw[EMBED_DIM];
  const int tid = threadIdx.x;
  sdw[tid] = (double)decw[tid];           // blockDim == EMBED_DIM == 256
  __syncthreads();
  const int c = blockIdx.x * 256 + tid;
  const float4* e4 = (const float4*)(emb + c * EMBED_DIM);
  double s = 0.0;
  #pragma unroll 8
  for (int q = 0; q < EMBED_DIM / 4; ++q) {
    const float4 v = e4[q];               // per-lane sequential 16B stream
    const int j = q * 4;                  // sdw reads: uniform idx -> broadcast
    s = fma((double)v.x, sdw[j + 0], s);
    s = fma((double)v.y, sdw[j + 1], s);
    s = fma((double)v.z, sdw[j + 2], s);
    s = fma((double)v.w, sdw[j + 3], s);
  }
  code_out[c] = s + (double)decb[0];
}

// P0c: per-interval affine (A,B) per code. Thread = (interval, code-half).
// w2 row as float4 stream (L2-resident, 256 KB); wj/bj LDS broadcast.
__global__ void __launch_bounds__(256) k_tables(
    const float* __restrict__ w1, const float* __restrict__ b1,
    const float* __restrict__ w2, const float* __restrict__ b2,
    const double* __restrict__ t_sorted, double2* __restrict__ AB) {
  __shared__ double wj[HIDDEN], bj[HIDDEN];
  const int i = blockIdx.x >> 1;
  const int c = ((blockIdx.x & 1) << 8) + threadIdx.x;
  const int tid = threadIdx.x;
  double xm;
  if (i == 0)            xm = t_sorted[0] - 1.0;
  else if (i == HIDDEN)  xm = t_sorted[HIDDEN - 1] + 1.0;
  else                   xm = 0.5 * (t_sorted[i - 1] + t_sorted[i]);
  if (tid < HIDDEN) {
    double w = (double)w1[tid], b = (double)b1[tid];
    bool act = fma(w, xm, b) > 0.0;       // relu sign constant in open interval
    wj[tid] = act ? w : 0.0;
    bj[tid] = act ? b : 0.0;
  }
  __syncthreads();
  const float4* r4 = (const float4*)(w2 + c * HIDDEN);
  double A = 0.0, Bv = 0.0;
  #pragma unroll 8
  for (int q = 0; q < HIDDEN / 4; ++q) {
    const float4 v = r4[q];
    const int j = q * 4;
    A  = fma((double)v.x, wj[j + 0], A);
    A  = fma((double)v.y, wj[j + 1], A);
    A  = fma((double)v.z, wj[j + 2], A);
    A  = fma((double)v.w, wj[j + 3], A);
    Bv = fma((double)v.x, bj[j + 0], Bv);
    Bv = fma((double)v.y, bj[j + 1], Bv);
    Bv = fma((double)v.z, bj[j + 2], Bv);
    Bv = fma((double)v.w, bj[j + 3], Bv);
  }
  AB[(i << 9) + c] = make_double2(A, Bv + (double)b2[c]);
}

// P1: branchless pairwise envelope membership. Line l survives iff not
// dominated by an equal-slope line and L = max_{A_k<A_l} x* < U = min_{A_k>A_l} x*.
// L as fraction (nL,dL), dL>=0 (dL==0 => -inf); U as (nU,dU), dU<=0
// (dU==0 => +inf; negative-denominator convention unifies both compares).
// Block = 4 waves; wave w scans k in [w*128,(w+1)*128) (wave-uniform LDS
// broadcast reads); 8 blocks per interval each own 64 lines; LDS merge.
__global__ void __launch_bounds__(256) k_env1(const double2* __restrict__ AB,
                       unsigned char* __restrict__ surv, double* __restrict__ Lx,
                       int* __restrict__ env_cnt) {
  __shared__ double2 sAB[NUM_CODES];
  __shared__ double sNL[4][64], sDL[4][64], sNU[4][64], sDU[4][64];
  __shared__ int sDead[4][64];
  const int tid = threadIdx.x;
  const int i = blockIdx.x >> 3;        // interval
  const int g = blockIdx.x & 7;         // line group
  const int w = tid >> 6, lane = tid & 63;
  const int c = (g << 6) + lane;        // my line
  const double2* row = AB + (i << 9);
  for (int t = tid; t < NUM_CODES; t += 256) sAB[t] = row[t];
  __syncthreads();
  const double2 my = sAB[c];
  double nL = -1.0, dL = 0.0, nU = -1.0, dU = 0.0;
  int dead = 0;
  const int k0 = w << 7;
  #pragma unroll 4
  for (int kk = 0; kk < 128; ++kk) {
    const int k = k0 + kk;
    const double2 o = sAB[k];           // wave-uniform -> LDS broadcast
    const double d = my.x - o.x;        // A_l - A_k
    const double n = o.y - my.y;        // B_k - B_l   (x* = n/d)
    const bool condL = (d > 0.0) && (n * dL > nL * d);
    const bool condU = (d < 0.0) && (n * dU < nU * d);
    nL = condL ? n : nL;  dL = condL ? d : dL;
    nU = condU ? n : nU;  dU = condU ? d : dU;
    dead |= (d == 0.0) && ((n > 0.0) || (n == 0.0 && k < c));
  }
  sNL[w][lane] = nL; sDL[w][lane] = dL;
  sNU[w][lane] = nU; sDU[w][lane] = dU;
  sDead[w][lane] = dead;
  __syncthreads();
  if (tid < 64) {                       // wave 0 merges the 4 k-chunks
    #pragma unroll
    for (int wv = 1; wv < 4; ++wv) {
      double cn = sNL[wv][lane], cd = sDL[wv][lane];
      if (cn * dL > nL * cd) { nL = cn; dL = cd; }   // valid incl. 0-sentinels
      cn = sNU[wv][lane]; cd = sDU[wv][lane];
      if (cn * dU < nU * cd) { nU = cn; dU = cd; }
      dead |= sDead[wv][lane];
    }
    // L < U with dL>=0, dU<=0: multiply by dL*dU (<0) flips: nL*dU > nU*dL
    const int sv = (!dead) && (dL == 0.0 || dU == 0.0 || (nL * dU > nU * dL));
    const int pair = (i << 9) + c;
    surv[pair] = (unsigned char)sv;
    Lx[pair]   = (dL == 0.0) ? -1e300 : nL / dL;
    const unsigned long long m = __ballot(sv);
    if (lane == 0) atomicAdd(&env_cnt[i], (int)__popcll(m));
  }
}

// P2: compact survivors into per-interval slope-sorted segment tables.
// rank = #survivors with smaller slope (survivor slopes are distinct).
__global__ void __launch_bounds__(256) k_env2(const double2* __restrict__ AB,
                       const unsigned char* __restrict__ surv,
                       const double* __restrict__ Lx,
                       double* __restrict__ env_xs, int* __restrict__ env_idx) {
  __shared__ double sA[NUM_CODES];
  const int tid = threadIdx.x;
  const int i = blockIdx.x >> 1;
  const int c = ((blockIdx.x & 1) << 8) + tid;
  const int base = i << 9;
  for (int t = tid; t < NUM_CODES; t += 256)
    sA[t] = surv[base + t] ? AB[base + t].x : 1e300;
  __syncthreads();
  const double myA = sA[c];
  int rank = 0;
  #pragma unroll 8
  for (int k = 0; k < NUM_CODES; ++k) rank += (sA[k] < myA) ? 1 : 0;
  if (surv[base + c]) {
    env_xs[base + rank]  = Lx[base + c];
    env_idx[base + rank] = c;
  }
}

// P3: per-sample lookup: classify interval (LDS), binary search segment starts.
__global__ void __launch_bounds__(256) k_map(const float* __restrict__ x,
                       const double* __restrict__ t_sorted,
                       const int* __restrict__ env_cnt,
                       const double* __restrict__ env_xs,
                       const int* __restrict__ env_idx,
                       const double* __restrict__ code_out,
                       float* __restrict__ out, float* __restrict__ idx_out) {
  __shared__ double ts[HIDDEN];
  __shared__ double sco[NUM_CODES];
  __shared__ int scnt[NUM_INT];
  const int tid = threadIdx.x;
  if (tid < HIDDEN) ts[tid] = t_sorted[tid];
  if (tid < NUM_INT) scnt[tid] = env_cnt[tid];
  for (int t = tid; t < NUM_CODES; t += 256) sco[t] = code_out[t];
  __syncthreads();
  const int s = blockIdx.x * 256 + tid;
  const double xv = (double)x[s];
  const int i = classify(ts, xv);
  const int base = i << 9;
  int lo = 0, hi = scnt[i] - 1;
  while (lo < hi) {                     // largest j with xs[j] <= xv
    const int mid = (lo + hi + 1) >> 1;
    if (env_xs[base + mid] <= xv) lo = mid; else hi = mid - 1;
  }
  const int ci = env_idx[base + lo];
  out[s]     = (float)sco[ci];
  idx_out[s] = (float)ci;
}

extern "C" void kernel_launch(void* const* d_in, const int* in_sizes, int n_in,
                              void* d_out, int out_size, void* d_ws, size_t ws_size,
                              hipStream_t stream) {
  const float* x    = (const float*)d_in[0];
  const float* w1   = (const float*)d_in[1];
  const float* b1   = (const float*)d_in[2];
  const float* w2   = (const float*)d_in[3];
  const float* b2   = (const float*)d_in[4];
  const float* emb  = (const float*)d_in[5];
  const float* decw = (const float*)d_in[6];
  const float* decb = (const float*)d_in[7];

  char* ws = (char*)d_ws;
  double*        t_sorted = (double*)        (ws + 0);
  double*        code_out = (double*)        (ws + 2048);
  int*           env_cnt  = (int*)           (ws + 8192);
  unsigned char* surv     = (unsigned char*) (ws + 9216);
  double*        Lx       = (double*)        (ws + 75264);
  double2*       AB       = (double2*)       (ws + 603648);
  double*        env_xs   = (double*)        (ws + 1660416);
  int*           env_idx  = (int*)           (ws + 2188800);

  float* out  = (float*)d_out;
  float* idxo = out + B_SAMPLES;

  k_prep   <<<1,                   256, 0, stream>>>(w1, b1, t_sorted, env_cnt);
  k_codeout<<<NUM_CODES / 256,     256, 0, stream>>>(emb, decw, decb, code_out);
  k_tables <<<NUM_INT * 2,         256, 0, stream>>>(w1, b1, w2, b2, t_sorted, AB);
  k_env1   <<<NUM_INT * 8,         256, 0, stream>>>(AB, surv, Lx, env_cnt);
  k_env2   <<<NUM_INT * 2,         256, 0, stream>>>(AB, surv, Lx, env_xs, env_idx);
  k_map    <<<B_SAMPLES / 256,     256, 0, stream>>>(x, t_sorted, env_cnt, env_xs, env_idx, code_out, out, idxo);
}